// Round 5
// baseline (328.961 us; speedup 1.0000x reference)
//
#include <hip/hip_runtime.h>

#define NT 128            // 2 output columns per thread
#define RROWS 45          // output rows per block (multiple of 9!)
#define STRIP 256         // output cols per block
#define PW 264            // staged (x,y) pairs per row: STRIP + 8 halo
#define WID 1024
#define HEI 1024
#define OWD 1016          // valid conv output dim (1024 - 8)

typedef float v2f __attribute__((ext_vector_type(2)));

// compile-time for: indices are literal constants in the AST -> SROA-proof
template<int I> struct IC { static constexpr int v = I; };
template<int N, int I = 0, typename F>
__device__ __forceinline__ void sfor(F&& f) {
    if constexpr (I < N) { f(IC<I>{}); sfor<N, I + 1>(f); }
}

// guaranteed VOP3P packed fp32 (2 lanes/inst) — don't trust the vectorizer
static __device__ __forceinline__ v2f pkfma(v2f a, v2f b, v2f c) {
    v2f d;
    asm("v_pk_fma_f32 %0, %1, %2, %3" : "=v"(d) : "v"(a), "v"(b), "v"(c));
    return d;
}
static __device__ __forceinline__ v2f pkmul(v2f a, v2f b) {
    v2f d;
    asm("v_pk_mul_f32 %0, %1, %2" : "=v"(d) : "v"(a), "v"(b));
    return d;
}

__global__ __launch_bounds__(NT, 2)
void ssim_main(const float* __restrict__ X, const float* __restrict__ Y,
               const float* __restrict__ Wg, double* __restrict__ acc)
{
    // 9-row LDS ring; phase p writes rows 3p+9..3p+11 (slots {3q..3q+2} mod 9),
    // reads rows 3p+8..3p+10 (slots {3q+8,3q,3q+1}) -> next phase's writes are
    // disjoint from this phase's reads: ONE barrier per 3-row phase.
    __shared__ float4 Prow[9][PW / 2];   // [slot][i] = (x_{2i}, y_{2i}, x_{2i+1}, y_{2i+1})
    __shared__ float  wsum[2][2];

    const int t  = threadIdx.x;
    const int r0 = blockIdx.x * RROWS;          // multiple of 9
    const int c0 = blockIdx.y * STRIP;
    const size_t ibase = (size_t)blockIdx.z * (size_t)(WID * HEI);
    const bool hcond = (t < 4) && (c0 + STRIP < WID);   // halo loader

    // 1D gaussian from row 4 of w2d, normalized; broadcast pairs in VGPRs
    v2f g2[9];
    {
        float gt[9]; float s = 0.f;
        sfor<9>([&](auto K) { constexpr int k = decltype(K)::v;
            gt[k] = Wg[36 + k]; s += gt[k]; });
        float rs = __builtin_amdgcn_rcpf(s);
        sfor<9>([&](auto K) { constexpr int k = decltype(K)::v;
            float gk = gt[k] * rs; g2[k] = (v2f){gk, gk}; });
    }

    const float C1 = 0.0004f, C2 = 0.0036f;
    float ssim_acc = 0.f, l1_acc = 0.f;

    // register ring: 9 rows x 5 channels x 2 cols = 90 VGPRs
    v2f  rA01[9], rA23[9], rB01[9], rB23[9];
    float rA4[9], rB4[9];
    // 3-row pending global-load pipeline
    float2 px_[3], py_[3], hx_[3], hy_[3];

    const float2* __restrict__ Xp = (const float2*)(X + ibase + c0);
    const float2* __restrict__ Yp = (const float2*)(Y + ibase + c0);

    auto issue = [&](int ro, auto S) {           // load row r0+ro -> pending s
        constexpr int s = decltype(S)::v;
        const int row = r0 + ro;
        if (row < HEI) {
            const size_t rb = (size_t)row * (WID / 2);
            px_[s] = Xp[rb + t];  py_[s] = Yp[rb + t];
            if (hcond) { hx_[s] = Xp[rb + 128 + t]; hy_[s] = Yp[rb + 128 + t]; }
        }
    };
    auto store = [&](int ro, auto S, auto LS) {  // pending s -> LDS slot ls (+L1)
        constexpr int s  = decltype(S)::v;
        constexpr int ls = decltype(LS)::v;
        const int row = r0 + ro;
        if (row < HEI) {
            Prow[ls][t] = make_float4(px_[s].x, py_[s].x, px_[s].y, py_[s].y);
            if (hcond) Prow[ls][128 + t] = make_float4(hx_[s].x, hy_[s].x, hx_[s].y, hy_[s].y);
            if (ro < RROWS)   // exclusively-owned rows/cols
                l1_acc += fabsf(px_[s].x - py_[s].x) + fabsf(px_[s].y - py_[s].y);
        }
    };

    // horizontal 9-tap conv, 5 ch x 2 cols (cols 2t, 2t+1), LDS slot -> ring
    auto hcomp2 = [&](auto LS, auto RS) {
        constexpr int ls = decltype(LS)::v;
        constexpr int rs = decltype(RS)::v;
        const float4* rowp = &Prow[ls][0];
        v2f a[10];
        sfor<5>([&](auto I) { constexpr int i = decltype(I)::v;
            float4 f = rowp[t + i];
            a[2 * i]     = (v2f){f.x, f.y};
            a[2 * i + 1] = (v2f){f.z, f.w};
        });
        v2f aa[10]; float xy[10];
        sfor<10>([&](auto E) { constexpr int e = decltype(E)::v;
            aa[e] = pkmul(a[e], a[e]);
            xy[e] = a[e].x * a[e].y;
        });
        v2f hA01 = (v2f)0.f, hA23 = (v2f)0.f, hB01 = (v2f)0.f, hB23 = (v2f)0.f;
        float hA4 = 0.f, hB4 = 0.f;
        sfor<9>([&](auto K) { constexpr int k = decltype(K)::v;
            hA01 = pkfma(g2[k], a[k],      hA01);
            hA23 = pkfma(g2[k], aa[k],     hA23);
            hA4  = fmaf(g2[k].x, xy[k],     hA4);
            hB01 = pkfma(g2[k], a[k + 1],  hB01);
            hB23 = pkfma(g2[k], aa[k + 1], hB23);
            hB4  = fmaf(g2[k].x, xy[k + 1], hB4);
        });
        rA01[rs] = hA01; rA23[rs] = hA23; rA4[rs] = hA4;
        rB01[rs] = hB01; rB23[rs] = hB23; rB4[rs] = hB4;
    };

    const bool vA = (c0 + 2 * t < OWD);
    const bool vB = (c0 + 2 * t + 1 < OWD);

    auto outrow2 = [&](int j, auto JM) {     // vertical 9-tap + SSIM, 2 cols
        constexpr int jm = decltype(JM)::v;
        if (r0 + j < OWD) {                  // block-uniform guard
            v2f uA01 = (v2f)0.f, uA23 = (v2f)0.f, uB01 = (v2f)0.f, uB23 = (v2f)0.f;
            float uA4 = 0.f, uB4 = 0.f;
            sfor<9>([&](auto K) { constexpr int k = decltype(K)::v;
                constexpr int s = (jm + k) % 9;
                uA01 = pkfma(g2[k], rA01[s], uA01);
                uA23 = pkfma(g2[k], rA23[s], uA23);
                uA4  = fmaf(g2[k].x, rA4[s], uA4);
                uB01 = pkfma(g2[k], rB01[s], uB01);
                uB23 = pkfma(g2[k], rB23[s], uB23);
                uB4  = fmaf(g2[k].x, rB4[s], uB4);
            });
            auto nb = [&](v2f u01, v2f u23, float uxy, float& n, float& b) {
                v2f uu = pkmul(u01, u01);          // (ux^2, uy^2)
                float sq   = uu.x + uu.y;
                float uxuy = u01.x * u01.y;
                float A1 = fmaf(2.f, uxuy, C1);
                float A2 = fmaf(2.f, uxy - uxuy, C2);
                float B1 = sq + C1;
                float B2 = (u23.x + u23.y) - sq + C2;
                n = A1 * A2; b = B1 * B2;
            };
            float nA, bA, nB, bB;
            nb(uA01, uA23, uA4, nA, bA);
            nb(uB01, uB23, uB4, nB, bB);
            nA = vA ? nA : 0.f;
            nB = vB ? nB : 0.f;
            float num = fmaf(nA, bB, nB * bA);     // SA+SB with a single rcp
            ssim_acc = fmaf(num, __builtin_amdgcn_rcpf(bA * bB), ssim_acc);
        }
    };

    // ---- prologue: rows 0..8 staged; hcomp rows 0..7 (row 8 in steady)
    issue(0, IC<0>{}); issue(1, IC<1>{}); issue(2, IC<2>{});
    store(0, IC<0>{}, IC<0>{}); store(1, IC<1>{}, IC<1>{}); store(2, IC<2>{}, IC<2>{});
    __syncthreads();
    issue(3, IC<0>{}); issue(4, IC<1>{}); issue(5, IC<2>{});
    hcomp2(IC<0>{}, IC<0>{}); hcomp2(IC<1>{}, IC<1>{}); hcomp2(IC<2>{}, IC<2>{});

    store(3, IC<0>{}, IC<3>{}); store(4, IC<1>{}, IC<4>{}); store(5, IC<2>{}, IC<5>{});
    __syncthreads();
    issue(6, IC<0>{}); issue(7, IC<1>{}); issue(8, IC<2>{});
    hcomp2(IC<3>{}, IC<3>{}); hcomp2(IC<4>{}, IC<4>{}); hcomp2(IC<5>{}, IC<5>{});

    store(6, IC<0>{}, IC<6>{}); store(7, IC<1>{}, IC<7>{}); store(8, IC<2>{}, IC<8>{});
    __syncthreads();
    issue(9, IC<0>{}); issue(10, IC<1>{}); issue(11, IC<2>{});
    hcomp2(IC<6>{}, IC<6>{}); hcomp2(IC<7>{}, IC<7>{});

    // ---- steady: 15 phases x 3 output rows, one barrier per phase
#pragma unroll 1
    for (int P = 0; P < 5; ++P) {
        sfor<3>([&](auto Q) {
            constexpr int q = decltype(Q)::v;
            const int p  = 3 * P + q;
            const int j0 = 9 * P + 3 * q;
            store(j0 + 9,  IC<0>{}, IC<(3 * q) % 9>{});
            store(j0 + 10, IC<1>{}, IC<(3 * q + 1) % 9>{});
            store(j0 + 11, IC<2>{}, IC<(3 * q + 2) % 9>{});
            __syncthreads();
            if (p < 14) {   // prefetch rows 3p+12..3p+14 (consumed next phase)
                issue(j0 + 12, IC<0>{}); issue(j0 + 13, IC<1>{}); issue(j0 + 14, IC<2>{});
            }
            hcomp2(IC<(3 * q + 8) % 9>{}, IC<(3 * q + 8) % 9>{});
            outrow2(j0,     IC<(3 * q) % 9>{});
            hcomp2(IC<(3 * q + 9) % 9>{}, IC<(3 * q + 9) % 9>{});
            outrow2(j0 + 1, IC<(3 * q + 1) % 9>{});
            hcomp2(IC<(3 * q + 10) % 9>{}, IC<(3 * q + 10) % 9>{});
            outrow2(j0 + 2, IC<(3 * q + 2) % 9>{});
        });
    }

    // ---- reduction: wave shfl -> LDS -> one double atomic pair per block
#pragma unroll
    for (int off = 32; off > 0; off >>= 1) {
        ssim_acc += __shfl_down(ssim_acc, off);
        l1_acc   += __shfl_down(l1_acc, off);
    }
    const int wid = t >> 6;
    if ((t & 63) == 0) { wsum[wid][0] = ssim_acc; wsum[wid][1] = l1_acc; }
    __syncthreads();
    if (t == 0) {
        double s = (double)wsum[0][0] + (double)wsum[1][0];
        double l = (double)wsum[0][1] + (double)wsum[1][1];
        atomicAdd(acc + 0, s);
        atomicAdd(acc + 1, l);
    }
}

__global__ void ssim_final(const double* __restrict__ acc, float* __restrict__ out)
{
    const double n_ssim = 33032192.0;   // 32*1016*1016
    const double n_l1   = 33554432.0;   // 32*1024*1024
    double ssim_loss = 1.0 - acc[0] / n_ssim;
    double l1        = acc[1] / n_l1;
    out[0] = (float)(0.5 * ssim_loss + 1.0 * l1);
}

extern "C" void kernel_launch(void* const* d_in, const int* in_sizes, int n_in,
                              void* d_out, int out_size, void* d_ws, size_t ws_size,
                              hipStream_t stream)
{
    const float* X  = (const float*)d_in[0];
    const float* Y  = (const float*)d_in[1];
    const float* Wg = (const float*)d_in[2];
    float*  out = (float*)d_out;
    double* acc = (double*)d_ws;

    hipMemsetAsync(acc, 0, 2 * sizeof(double), stream);
    dim3 grid(23, 4, 32);   // rowblocks(ceil(1016/45)) x col-strips x images
    ssim_main<<<grid, NT, 0, stream>>>(X, Y, Wg, acc);
    ssim_final<<<1, 1, 0, stream>>>(acc, out);
}